// Round 19
// baseline (48.371 us; speedup 1.0000x reference)
//
#include <hip/hip_runtime.h>

#define NN 1024
#define DD 128

// ---- fast math helpers ----
// v_rcp_f32 is ~1 ulp on gfx950; NO Newton step (NR turns inf into NaN).
__device__ __forceinline__ float frcp(float x) {
  return __builtin_amdgcn_rcpf(x);
}
__device__ __forceinline__ float fsqrt(float x) {
  return __builtin_amdgcn_sqrtf(x);
}
// artanh(z)/z with reference-style clipping (z >= 0)
__device__ __forceinline__ float artanh_ratio(float z) {
  z = fminf(z, 1.0f - 1e-7f);
  if (z < 1e-4f) return 1.0f + z * z * (1.0f / 3.0f);
  return 0.5f * (__logf(1.0f + z) - __logf(1.0f - z)) * frcp(z);
}
// tanh(a) for a >= 0 via exp(-2a) in [0,1]: overflow-free, saturates to 1.
__device__ __forceinline__ float ftanh(float a) {
  const float e = __expf(-2.0f * a);
  return (1.0f - e) * frcp(1.0f + e);
}

// ---------------- MEGA2: k23 (proven R18 body) + 16-way partial sync + k4 ----------------
// Grid (16,16) x 512 thr. Block (bj,bi) produces Vp slab bj for rows of bi,
// releases cnt[bi]; blocks with bj<4 then finalize 16 rows each. Spinners:
// 64 total over 16 distinct cache lines (4 each) -- avoids the R14/R15
// single-line poll storm (256 pollers on 1 line ~ 25 us/barrier).
__global__ __launch_bounds__(512) void mega2(
    const float* __restrict__ x, const float* __restrict__ adj,
    const float* __restrict__ aw, const float* __restrict__ bptr,
    float* __restrict__ Vp, float* __restrict__ PA,
    unsigned* __restrict__ cnt, float* __restrict__ out) {
  __shared__ __align__(16) float xiT[DD * 64];  // 32 KB (aliased to u_lds later)
  __shared__ __align__(16) float xjT[DD * 64];  // 32 KB
  __shared__ float s_nx2i[64], s_lft[64], s_nx2j[64], s_rgt[64];
  const int t = threadIdx.x;
  const int bi = blockIdx.y, bj = blockIdx.x;
  const int tx = t & 15;        // j-quad (4 cols)
  const int ty = t >> 4;        // 0..31, i-pair (2 rows)
  const int gi0 = bi * 64 + ty * 2;
  const int gj0 = bj * 64 + tx * 4;

  // prefetch adj (2 rows x 4 cols)
  float4 ajv[2];
#pragma unroll
  for (int i = 0; i < 2; ++i)
    ajv[i] = *(const float4*)&adj[(size_t)(gi0 + i) * NN + gj0];
  const float attb = bptr[0];

  // stage k-major panels
  {
    const int r = t & 63;
    const int kq = t >> 6;  // 0..7, 16 k each
    const float* si = x + (bi * 64 + r) * DD + kq * 16;
    const float* sj = x + (bj * 64 + r) * DD + kq * 16;
#pragma unroll
    for (int m = 0; m < 4; ++m) {
      const int k0 = kq * 16 + m * 4;
      const float4 vi = *(const float4*)(si + m * 4);
      const float4 vj = *(const float4*)(sj + m * 4);
      xiT[(k0 + 0) * 64 + r] = vi.x;
      xiT[(k0 + 1) * 64 + r] = vi.y;
      xiT[(k0 + 2) * 64 + r] = vi.z;
      xiT[(k0 + 3) * 64 + r] = vi.w;
      xjT[(k0 + 0) * 64 + r] = vj.x;
      xjT[(k0 + 1) * 64 + r] = vj.y;
      xjT[(k0 + 2) * 64 + r] = vj.z;
      xjT[(k0 + 3) * 64 + r] = vj.w;
    }
  }
  __syncthreads();

  // per-node scalars: 4 threads per row (k split 4x32), shfl_xor(1,2) combine
  {
    const int r = (t >> 2) & 63;
    const int h = t & 3;
    const bool jp = (t >= 256);
    const float* panel = jp ? xjT : xiT;
    const float* wv = aw + (jp ? DD : 0);
    float sa = 0.0f, sb = 0.0f;
    const int k0 = h * 32;
#pragma unroll 8
    for (int k = 0; k < 32; ++k) {
      const float v = panel[(k0 + k) * 64 + r];
      sa = fmaf(v, v, sa);
      sb = fmaf(v, wv[k0 + k], sb);
    }
    sa += __shfl_xor(sa, 1, 64);
    sb += __shfl_xor(sb, 1, 64);
    sa += __shfl_xor(sa, 2, 64);
    sb += __shfl_xor(sb, 2, 64);
    if (h == 0) {
      const float pn = fmaxf(fsqrt(sa), 1e-15f);
      const float hh = artanh_ratio(pn);
      if (jp) { s_nx2j[r] = sa; s_rgt[r] = hh * sb; }
      else    { s_nx2i[r] = sa; s_lft[r] = hh * sb; }
    }
  }
  __syncthreads();

  // S-GEMM 2x4, 4-deep k batches
  float acc[2][4] = {};
#pragma unroll 2
  for (int kb = 0; kb < DD; kb += 4) {
    float2 A[4];
    float4 B[4];
#pragma unroll
    for (int q = 0; q < 4; ++q) {
      A[q] = *(const float2*)&xiT[(kb + q) * 64 + ty * 2];
      B[q] = *(const float4*)&xjT[(kb + q) * 64 + tx * 4];
    }
#pragma unroll
    for (int q = 0; q < 4; ++q) {
      acc[0][0] = fmaf(A[q].x, B[q].x, acc[0][0]);
      acc[0][1] = fmaf(A[q].x, B[q].y, acc[0][1]);
      acc[0][2] = fmaf(A[q].x, B[q].z, acc[0][2]);
      acc[0][3] = fmaf(A[q].x, B[q].w, acc[0][3]);
      acc[1][0] = fmaf(A[q].y, B[q].x, acc[1][0]);
      acc[1][1] = fmaf(A[q].y, B[q].y, acc[1][1]);
      acc[1][2] = fmaf(A[q].y, B[q].z, acc[1][2]);
      acc[1][3] = fmaf(A[q].y, B[q].w, acc[1][3]);
    }
  }

  // pair epilogue (proven formulas) -> u kept in registers
  float ny2v[4], rv[4];
#pragma unroll
  for (int j = 0; j < 4; ++j) {
    ny2v[j] = s_nx2j[tx * 4 + j];
    rv[j] = s_rgt[tx * 4 + j];
  }
  float4 ureg[2];
  float sua[2];
#pragma unroll
  for (int i = 0; i < 2; ++i) {
    const float xi2 = s_nx2i[ty * 2 + i];
    const float li = s_lft[ty * 2 + i];
    const float beta = 1.0f - xi2;
    const float betac = fmaxf(beta, 1e-15f);
    const float av[4] = {ajv[i].x, ajv[i].y, ajv[i].z, ajv[i].w};
    float u4[4];
    float ua = 0.0f;
#pragma unroll
    for (int j = 0; j < 4; ++j) {
      const float s = acc[i][j];
      const float al = 1.0f - 2.0f * s + ny2v[j];
      const float den = fmaxf(1.0f - 2.0f * s + xi2 * ny2v[j], 1e-15f);
      const float rden = frcp(den);
      float s2 = fmaxf(al * al * xi2 - 2.0f * al * beta * s + beta * beta * ny2v[j], 0.0f);
      s2 = s2 * rden * rden;
      const float sn = fmaxf(fsqrt(s2), 1e-15f);
      const float G = betac * artanh_ratio(sn);
      const float sig = frcp(1.0f + __expf(-(li + rv[j] + attb)));
      const float u = sig * av[j] * G * rden;
      u4[j] = u;
      ua = fmaf(u, al, ua);
    }
    ureg[i].x = u4[0]; ureg[i].y = u4[1]; ureg[i].z = u4[2]; ureg[i].w = u4[3];
    sua[i] = ua;
  }
#pragma unroll
  for (int m = 1; m < 16; m <<= 1) {
#pragma unroll
    for (int i = 0; i < 2; ++i) sua[i] += __shfl_xor(sua[i], m, 64);
  }
  if (tx == 0) {
#pragma unroll
    for (int i = 0; i < 2; ++i) PA[(gi0 + i) * 16 + bj] = sua[i];
  }

  // write u into LDS (aliases xiT; all xiT reads done)
  __syncthreads();
  float* u_lds = xiT;  // [64][64]
#pragma unroll
  for (int i = 0; i < 2; ++i)
    *(float4*)&u_lds[(ty * 2 + i) * 64 + tx * 4] = ureg[i];
  __syncthreads();

  // V GEMM: Vp[bj][gi][d] = sum_j u[i][j] * x[j][d]
  {
    const int tx2 = t & 31, ty2 = t >> 5;
    const int i0 = ty2 * 4, d0 = tx2 * 4;
    float4 a4[4];
#pragma unroll
    for (int ii = 0; ii < 4; ++ii) a4[ii] = make_float4(0.0f, 0.0f, 0.0f, 0.0f);
#pragma unroll 4
    for (int jb = 0; jb < 16; ++jb) {
      const int j0 = jb * 4;
      float4 xv[4];
#pragma unroll
      for (int jj = 0; jj < 4; ++jj)
        xv[jj] = *(const float4*)&x[(size_t)(bj * 64 + j0 + jj) * DD + d0];
      float4 uv[4];
#pragma unroll
      for (int ii = 0; ii < 4; ++ii)
        uv[ii] = *(const float4*)&u_lds[(i0 + ii) * 64 + j0];
#pragma unroll
      for (int ii = 0; ii < 4; ++ii) {
        a4[ii].x = fmaf(uv[ii].x, xv[0].x, fmaf(uv[ii].y, xv[1].x, fmaf(uv[ii].z, xv[2].x, fmaf(uv[ii].w, xv[3].x, a4[ii].x))));
        a4[ii].y = fmaf(uv[ii].x, xv[0].y, fmaf(uv[ii].y, xv[1].y, fmaf(uv[ii].z, xv[2].y, fmaf(uv[ii].w, xv[3].y, a4[ii].y))));
        a4[ii].z = fmaf(uv[ii].x, xv[0].z, fmaf(uv[ii].y, xv[1].z, fmaf(uv[ii].z, xv[2].z, fmaf(uv[ii].w, xv[3].z, a4[ii].z))));
        a4[ii].w = fmaf(uv[ii].x, xv[0].w, fmaf(uv[ii].y, xv[1].w, fmaf(uv[ii].z, xv[2].w, fmaf(uv[ii].w, xv[3].w, a4[ii].w))));
      }
    }
#pragma unroll
    for (int ii = 0; ii < 4; ++ii)
      *(float4*)&Vp[((size_t)bj * NN + bi * 64 + i0 + ii) * DD + d0] = a4[ii];
  }

  // ---- release: signal slab done (cnt zeroed by host-side memset) ----
  __syncthreads();  // drains vmcnt for ALL threads' Vp/PA stores
  if (t == 0) {
    __threadfence();
    atomicAdd(&cnt[bi], 1u);
  }
  if (bj >= 4) return;

  // ---- consumer: wait for all 16 slabs of group bi (4 spinners/line) ----
  if (t == 0) {
    while (__hip_atomic_load(&cnt[bi], __ATOMIC_RELAXED, __HIP_MEMORY_SCOPE_AGENT) < 16u)
      __builtin_amdgcn_s_sleep(2);
    __threadfence();  // acquire
  }
  __syncthreads();

  // ---- k4 phase (proven body): rows bi*64 + bj*16 .. +15, 2 rows/wave ----
  {
    const int l = t & 63;
    const int w8 = t >> 6;  // 0..7
#pragma unroll
    for (int r = 0; r < 2; ++r) {
      const int row = bi * 64 + bj * 16 + w8 * 2 + r;
      const float2 xv = *(const float2*)&x[row * DD + 2 * l];
      const float xi0 = xv.x, xi1 = xv.y;
      float ra = xi0 * xi0 + xi1 * xi1;
#pragma unroll
      for (int m = 1; m < 64; m <<= 1) ra += __shfl_xor(ra, m, 64);
      const float nx2i = ra;

      float v0 = 0.0f, v1 = 0.0f;
#pragma unroll
      for (int kt = 0; kt < 16; ++kt) {
        const float2 vv = *(const float2*)&Vp[((size_t)kt * NN + row) * DD + 2 * l];
        v0 += vv.x;
        v1 += vv.y;
      }
      float sa = (l < 16) ? PA[row * 16 + l] : 0.0f;
#pragma unroll
      for (int m = 1; m < 64; m <<= 1) sa += __shfl_xor(sa, m, 64);

      const float beta = 1.0f - nx2i;
      const float betac = fmaxf(beta, 1e-15f);
      const float u0 = beta * v0 - sa * xi0;
      const float u1 = beta * v1 - sa * xi1;
      float p0 = u0 * u0 + u1 * u1;
      float p1 = xi0 * u0 + xi1 * u1;
#pragma unroll
      for (int m = 1; m < 64; m <<= 1) {
        p0 += __shfl_xor(p0, m, 64);
        p1 += __shfl_xor(p1, m, 64);
      }
      const float un = fmaxf(fsqrt(p0), 1e-15f);
      const float tau = ftanh(frcp(betac) * un) * frcp(un);
      const float y2 = tau * tau * p0;
      const float xy = tau * p1;
      const float numx = 1.0f + 2.0f * xy + y2;
      const float dene = fmaxf(1.0f + 2.0f * xy + nx2i * y2, 1e-15f);
      const float rdene = frcp(dene);
      float r0 = (numx * xi0 + beta * tau * u0) * rdene;
      float r1 = (numx * xi1 + beta * tau * u1) * rdene;
      const float n2 = fmaxf(numx * numx * nx2i + 2.0f * numx * beta * xy + beta * beta * y2, 0.0f);
      const float n = fmaxf(fsqrt(n2) * rdene, 1e-15f);
      const float maxn = 1.0f - 4e-3f;  // (1-PROJ_EPS)/sqrt(c)
      if (n > maxn) {
        const float sc = maxn * frcp(n);
        r0 *= sc;
        r1 *= sc;
      }
      float2 ro; ro.x = r0; ro.y = r1;
      *(float2*)&out[row * DD + 2 * l] = ro;
    }
  }
}

// ---------------- Fallback: fused kernel (proven structure) ----------------
__global__ __launch_bounds__(256) void hypagg_fused(
    const float* __restrict__ x, const float* __restrict__ adj,
    const float* __restrict__ aw, const float* __restrict__ bptr,
    float* __restrict__ out) {
  __shared__ __align__(16) float xi_lds[4 * DD];
  __shared__ __align__(16) float w2_lds[DD];
  const int t = threadIdx.x;
  const int w = t >> 6;
  const int l = t & 63;
  const int row = blockIdx.x * 4 + w;

  xi_lds[t] = x[blockIdx.x * 4 * DD + t];
  xi_lds[t + 256] = x[blockIdx.x * 4 * DD + t + 256];
  if (t < DD) w2_lds[t] = aw[DD + t];
  __syncthreads();

  const float attb = bptr[0];
  const float* xi = &xi_lds[w * DD];
  const float xi0 = xi[l];
  const float xi1 = xi[l + 64];

  float ra = xi0 * xi0 + xi1 * xi1;
  float rb = xi0 * aw[l] + xi1 * aw[l + 64];
#pragma unroll
  for (int m = 1; m < 64; m <<= 1) {
    ra += __shfl_xor(ra, m, 64);
    rb += __shfl_xor(rb, m, 64);
  }
  const float nx2i = ra;
  const float beta = 1.0f - nx2i;
  const float betac = fmaxf(beta, 1e-15f);
  const float hi = artanh_ratio(fmaxf(fsqrt(nx2i), 1e-15f));
  const float lfti = hi * rb;

  float V0 = 0.0f, V1 = 0.0f, SA = 0.0f;

  for (int j0 = 0; j0 < NN; j0 += 64) {
    const int jj = j0 + l;
    const float* xj = x + jj * DD;
    float s = 0.0f, ny2 = 0.0f, rj = 0.0f;
#pragma unroll 8
    for (int k4 = 0; k4 < DD / 4; ++k4) {
      const float4 b4 = *(const float4*)(xj + k4 * 4);
      const float4 a4 = *(const float4*)(xi + k4 * 4);
      const float4 w4 = *(const float4*)(&w2_lds[k4 * 4]);
      s   = fmaf(a4.x, b4.x, fmaf(a4.y, b4.y, fmaf(a4.z, b4.z, fmaf(a4.w, b4.w, s))));
      ny2 = fmaf(b4.x, b4.x, fmaf(b4.y, b4.y, fmaf(b4.z, b4.z, fmaf(b4.w, b4.w, ny2))));
      rj  = fmaf(w4.x, b4.x, fmaf(w4.y, b4.y, fmaf(w4.z, b4.z, fmaf(w4.w, b4.w, rj))));
    }
    const float hj = artanh_ratio(fmaxf(fsqrt(ny2), 1e-15f));
    const float rgtj = hj * rj;
    const float al = 1.0f - 2.0f * s + ny2;
    const float den = fmaxf(1.0f - 2.0f * s + nx2i * ny2, 1e-15f);
    const float rden = frcp(den);
    float s2 = fmaxf(al * al * nx2i - 2.0f * al * beta * s + beta * beta * ny2, 0.0f);
    s2 = s2 * rden * rden;
    const float sn = fmaxf(fsqrt(s2), 1e-15f);
    const float G = betac * artanh_ratio(sn);
    const float sig = frcp(1.0f + __expf(-(lfti + rgtj + attb)));
    const float u = sig * adj[row * NN + jj] * G * rden;
    SA = fmaf(u, al, SA);
#pragma unroll 16
    for (int jq = 0; jq < 64; ++jq) {
      const float uq = __shfl(u, jq, 64);
      const float xd0 = x[(j0 + jq) * DD + l];
      const float xd1 = x[(j0 + jq) * DD + l + 64];
      V0 = fmaf(uq, xd0, V0);
      V1 = fmaf(uq, xd1, V1);
    }
  }

#pragma unroll
  for (int m = 1; m < 64; m <<= 1) SA += __shfl_xor(SA, m, 64);

  const float u0 = beta * V0 - SA * xi0;
  const float u1 = beta * V1 - SA * xi1;
  float p0 = u0 * u0 + u1 * u1;
  float p1 = xi0 * u0 + xi1 * u1;
#pragma unroll
  for (int m = 1; m < 64; m <<= 1) {
    p0 += __shfl_xor(p0, m, 64);
    p1 += __shfl_xor(p1, m, 64);
  }
  const float un = fmaxf(fsqrt(p0), 1e-15f);
  const float tau = ftanh(frcp(betac) * un) * frcp(un);
  const float y2 = tau * tau * p0;
  const float xy = tau * p1;
  const float numx = 1.0f + 2.0f * xy + y2;
  const float dene = fmaxf(1.0f + 2.0f * xy + nx2i * y2, 1e-15f);
  const float rdene = frcp(dene);
  float r0 = (numx * xi0 + beta * tau * u0) * rdene;
  float r1 = (numx * xi1 + beta * tau * u1) * rdene;
  const float n2 = fmaxf(numx * numx * nx2i + 2.0f * numx * beta * xy + beta * beta * y2, 0.0f);
  const float n = fmaxf(fsqrt(n2) * rdene, 1e-15f);
  const float maxn = 1.0f - 4e-3f;
  if (n > maxn) {
    const float sc = maxn * frcp(n);
    r0 *= sc;
    r1 *= sc;
  }
  out[row * DD + l] = r0;
  out[row * DD + l + 64] = r1;
}

extern "C" void kernel_launch(void* const* d_in, const int* in_sizes, int n_in,
                              void* d_out, int out_size, void* d_ws, size_t ws_size,
                              hipStream_t stream) {
  // Bind inputs BY SIZE (unique: x=131072, adj=1048576, att_w=256, att_b=1)
  const float* x = nullptr;
  const float* adj = nullptr;
  const float* aw = nullptr;
  const float* ab = nullptr;
  for (int i = 0; i < n_in; ++i) {
    switch (in_sizes[i]) {
      case NN * DD:  x   = (const float*)d_in[i]; break;
      case NN * NN:  adj = (const float*)d_in[i]; break;
      case 2 * DD:   aw  = (const float*)d_in[i]; break;
      case 1:        ab  = (const float*)d_in[i]; break;
      default: break;
    }
  }
  float* out = (float*)d_out;

  // ws layout: Vp [16*N*D] | PA [N*16] | cnt [16 u32]
  const size_t need = (16 * (size_t)NN * DD + NN * 16) * sizeof(float) + 16 * sizeof(unsigned);
  if (ws_size >= need) {
    float* Vp = (float*)d_ws;
    float* PA = Vp + 16 * (size_t)NN * DD;
    unsigned* cnt = (unsigned*)(PA + NN * 16);
    hipMemsetAsync((void*)cnt, 0, 16 * sizeof(unsigned), stream);
    hipLaunchKernelGGL(mega2, dim3(16, 16), dim3(512), 0, stream,
                       x, adj, aw, ab, Vp, PA, cnt, out);
  } else {
    hipLaunchKernelGGL(hypagg_fused, dim3(NN / 4), dim3(256), 0, stream,
                       x, adj, aw, ab, out);
  }
}